// Round 2
// baseline (1681.089 us; speedup 1.0000x reference)
//
#include <hip/hip_runtime.h>

// ---------------- problem dims ----------------
#define IN_F  128
#define GHID  512
#define NHID  128
#define NTOK  196608L   // 1024 * 192
#define LDSP  520       // LDS row pitch in bf16 elems (512 + 8 pad)

typedef __attribute__((ext_vector_type(8))) short short8;
typedef __attribute__((ext_vector_type(4))) float floatx4;

// ---------------- ws layout ----------------
// bf16 packed weights (ushort elems), fragment order:
//   frag index = ((gate*(H/16) + tn) * (K/32) + tk), 512 elems per frag,
//   elem (lane,j): row n = tn*16 + (lane&15), col k = tk*32 + (lane>>4)*8 + j
#define O_GW0 0L
#define O_GW1 196608L
#define O_GW2 983040L
#define O_NW0 1769472L
#define O_NW1 1818624L
#define NWS   1867776L
// fp32 region (float elems), base byte = NWS*2
#define F_GB0 0
#define F_GB1 1536
#define F_GB2 3072
#define F_NB0 4608
#define F_NB1 4992
#define F_WE  5376
#define F_AW  5888
#define F_BE  6016
#define F_AB  6017
#define NFLT  6018

__device__ __forceinline__ unsigned short f2bf(float f) {
  unsigned int u = __float_as_uint(f);
  u += 0x7fffu + ((u >> 16) & 1u);      // RNE
  return (unsigned short)(u >> 16);
}
__device__ __forceinline__ float fsigm(float x) {
  return __builtin_amdgcn_rcpf(1.f + __expf(-x));
}
__device__ __forceinline__ float ftanh(float x) {
  return 1.f - 2.f * __builtin_amdgcn_rcpf(1.f + __expf(2.f * x));
}

// ---------------- prep kernel: repack weights ----------------
__device__ __forceinline__ long srcoff(long pp, int H, int K) {
  long f = pp >> 9;
  int r = (int)(pp & 511);
  int ln = r >> 3, j = r & 7;
  int nKT = K >> 5, nCT = H >> 4;
  int tk = (int)(f % nKT);
  long t2 = f / nKT;
  int tn = (int)(t2 % nCT);
  int gate = (int)(t2 / nCT);
  int n = tn * 16 + (ln & 15);
  int k = tk * 32 + ((ln >> 4) << 3) + j;
  int go = (gate == 0) ? 0 : ((gate == 1) ? 2 * H : 3 * H);  // i, c, o rows
  return (long)(go + n) * K + k;
}

__global__ void prep_kernel(
    const float* __restrict__ gW0, const float* __restrict__ gbi0, const float* __restrict__ gbh0,
    const float* __restrict__ gW,  const float* __restrict__ gbi,  const float* __restrict__ gbh,
    const float* __restrict__ eW,  const float* __restrict__ eb,
    const float* __restrict__ nW0, const float* __restrict__ nbi0, const float* __restrict__ nbh0,
    const float* __restrict__ nW,  const float* __restrict__ nbi,  const float* __restrict__ nbh,
    const float* __restrict__ aW,  const float* __restrict__ ab,
    unsigned short* __restrict__ wpk, float* __restrict__ fpk)
{
  long idx = (long)blockIdx.x * blockDim.x + threadIdx.x;
  if (idx < NWS) {
    const float* src;
    long off;
    if (idx < O_GW1)      { off = srcoff(idx - O_GW0, 512, 128); src = gW0; }
    else if (idx < O_GW2) { off = srcoff(idx - O_GW1, 512, 512); src = gW; }
    else if (idx < O_NW0) { off = srcoff(idx - O_GW2, 512, 512); src = gW + 1048576; }
    else if (idx < O_NW1) { off = srcoff(idx - O_NW0, 128, 128); src = nW0; }
    else                  { off = srcoff(idx - O_NW1, 128, 128); src = nW; }
    wpk[idx] = f2bf(src[off]);
    return;
  }
  long p = idx - NWS;
  if (p < 1536) { int g = (int)(p >> 9), n = (int)(p & 511);
    int o = (g == 0 ? 0 : (g == 1 ? 1024 : 1536)) + n;
    fpk[F_GB0 + p] = gbi0[o] + gbh0[o]; return; }
  p -= 1536;
  if (p < 1536) { int g = (int)(p >> 9), n = (int)(p & 511);
    int o = (g == 0 ? 0 : (g == 1 ? 1024 : 1536)) + n;
    fpk[F_GB1 + p] = gbi[o] + gbh[o]; return; }
  p -= 1536;
  if (p < 1536) { int g = (int)(p >> 9), n = (int)(p & 511);
    int o = (g == 0 ? 0 : (g == 1 ? 1024 : 1536)) + n;
    fpk[F_GB2 + p] = gbi[2048 + o] + gbh[2048 + o]; return; }
  p -= 1536;
  if (p < 384) { int g = (int)(p / 128), n = (int)(p % 128);
    int o = (g == 0 ? 0 : (g == 1 ? 256 : 384)) + n;
    fpk[F_NB0 + p] = nbi0[o] + nbh0[o]; return; }
  p -= 384;
  if (p < 384) { int g = (int)(p / 128), n = (int)(p % 128);
    int o = (g == 0 ? 0 : (g == 1 ? 256 : 384)) + n;
    fpk[F_NB1 + p] = nbi[o] + nbh[o]; return; }
  p -= 384;
  if (p < 512) { float s = 0.f;
    for (int f = 0; f < 10; ++f) s += eW[f * 512 + p];
    fpk[F_WE + p] = s; return; }
  p -= 512;
  if (p < 128) { fpk[F_AW + p] = aW[p]; return; }
  p -= 128;
  if (p == 0) { float s = 0.f; for (int f = 0; f < 10; ++f) s += eb[f]; fpk[F_BE] = s; return; }
  if (p == 1) { fpk[F_AB] = ab[0]; return; }
}

// ---------------- fused main kernel ----------------
// Layer engine. MODE 0: LSTM-cell combine -> hold bf16 in hh[] (writeback later).
//               MODE 1: LSTM-cell combine -> relu -> dot with dotw -> LDS atomics into accVec.
// NW = col-tile stride between cp passes (== #participating waves).
template <int K, int H, int CPW, int MODE, int NW>
__device__ __forceinline__ void layer_run(
    const unsigned short* __restrict__ sIn,   // LDS input base (col offset applied)
    const unsigned short* __restrict__ wp,    // packed weights for this layer
    const float* __restrict__ bias,           // [3*H] gate-major fused biases
    const float* __restrict__ dotw,           // MODE 1: fp32 [H]
    float* accVec,                            // MODE 1: LDS [64]
    unsigned int hh[][2],                     // MODE 0: [CPW*4][2] packed bf16
    int wave, int lane)
{
  constexpr int nKT = K / 32;
  constexpr int nCT = H / 16;
  float vv[4][4];
  if constexpr (MODE == 1) {
#pragma unroll
    for (int tt = 0; tt < 4; ++tt)
#pragma unroll
      for (int r = 0; r < 4; ++r) vv[tt][r] = 0.f;
  }
#pragma unroll
  for (int cp = 0; cp < CPW; ++cp) {
    int tn = wave + cp * NW;
    floatx4 acc[3][4] = {};
    const unsigned short* wbase = wp + (size_t)tn * nKT * 512 + lane * 8;
    const unsigned short* aBase = sIn + (size_t)(lane & 15) * LDSP + ((lane >> 4) << 3);
#pragma unroll 4
    for (int ks = 0; ks < nKT; ++ks) {
      short8 b0 = *(const short8*)(wbase + (size_t)ks * 512);
      short8 b1 = *(const short8*)(wbase + (size_t)(nCT * nKT + ks) * 512);
      short8 b2 = *(const short8*)(wbase + (size_t)(2 * nCT * nKT + ks) * 512);
#pragma unroll
      for (int tt = 0; tt < 4; ++tt) {
        short8 a = *(const short8*)(aBase + (size_t)tt * 16 * LDSP + ks * 32);
        acc[0][tt] = __builtin_amdgcn_mfma_f32_16x16x32_bf16(a, b0, acc[0][tt], 0, 0, 0);
        acc[1][tt] = __builtin_amdgcn_mfma_f32_16x16x32_bf16(a, b1, acc[1][tt], 0, 0, 0);
        acc[2][tt] = __builtin_amdgcn_mfma_f32_16x16x32_bf16(a, b2, acc[2][tt], 0, 0, 0);
      }
    }
    int colg = tn * 16 + (lane & 15);
    float bi = bias[colg], bc = bias[H + colg], bo = bias[2 * H + colg];
    float dw = 0.f;
    if constexpr (MODE == 1) dw = dotw[colg];
#pragma unroll
    for (int tt = 0; tt < 4; ++tt) {
      unsigned int p0 = 0, p1 = 0;
#pragma unroll
      for (int r = 0; r < 4; ++r) {
        float gi = acc[0][tt][r] + bi;
        float gc = acc[1][tt][r] + bc;
        float go = acc[2][tt][r] + bo;
        float h = fsigm(go) * ftanh(fsigm(gi) * ftanh(gc));
        if constexpr (MODE == 0) {
          unsigned int us = f2bf(h);
          if (r == 0) p0 = us;
          else if (r == 1) p0 |= us << 16;
          else if (r == 2) p1 = us;
          else p1 |= us << 16;
        } else {
          vv[tt][r] += fmaxf(h, 0.f) * dw;
        }
      }
      if constexpr (MODE == 0) { hh[cp * 4 + tt][0] = p0; hh[cp * 4 + tt][1] = p1; }
    }
  }
  if constexpr (MODE == 1) {
#pragma unroll
    for (int tt = 0; tt < 4; ++tt)
#pragma unroll
      for (int r = 0; r < 4; ++r) {
        float v = vv[tt][r];
        v += __shfl_xor(v, 1, 16);
        v += __shfl_xor(v, 2, 16);
        v += __shfl_xor(v, 4, 16);
        v += __shfl_xor(v, 8, 16);
        if ((lane & 15) == 0)
          atomicAdd(&accVec[tt * 16 + ((lane >> 4) << 2) + r], v);
      }
  }
}

template <int CPW, int NW>
__device__ __forceinline__ void writeback(unsigned short* sOut, unsigned int hh[][2],
                                          int wave, int lane) {
#pragma unroll
  for (int cp = 0; cp < CPW; ++cp) {
    int tn = wave + cp * NW;
    int col = tn * 16 + (lane & 15);
#pragma unroll
    for (int tt = 0; tt < 4; ++tt) {
      int row = tt * 16 + ((lane >> 4) << 2);
      unsigned int p0 = hh[cp * 4 + tt][0], p1 = hh[cp * 4 + tt][1];
      sOut[(size_t)(row + 0) * LDSP + col] = (unsigned short)(p0 & 0xffffu);
      sOut[(size_t)(row + 1) * LDSP + col] = (unsigned short)(p0 >> 16);
      sOut[(size_t)(row + 2) * LDSP + col] = (unsigned short)(p1 & 0xffffu);
      sOut[(size_t)(row + 3) * LDSP + col] = (unsigned short)(p1 >> 16);
    }
  }
}

// 512 threads = 8 waves/block; 2 blocks/CU (LDS 67 KB x2); VGPR cap 128 -> no spills.
__global__ __launch_bounds__(512, 4) void dfrnn_main(
    const float* __restrict__ X,
    const unsigned short* __restrict__ wpk,
    const float* __restrict__ fpk,
    float* __restrict__ out)
{
  __shared__ __align__(16) unsigned short sH[64 * LDSP];
  __shared__ float accMu[64];
  __shared__ float accSt[64];
  int tid = threadIdx.x;
  int wave = tid >> 6, lane = tid & 63;
  size_t blkTok = (size_t)blockIdx.x * 64;

  if (tid < 64) { accMu[tid] = 0.f; accSt[tid] = 0.f; }
  // load X tile [64 x 128] fp32 -> bf16 into sH cols 0..127
  for (int i = tid; i < 64 * 32; i += 512) {
    int row = i >> 5, c4 = i & 31;
    float4 v = *(const float4*)(X + (blkTok + row) * 128 + c4 * 4);
    ushort4 b;
    b.x = f2bf(v.x); b.y = f2bf(v.y); b.z = f2bf(v.z); b.w = f2bf(v.w);
    *(ushort4*)&sH[(size_t)row * LDSP + c4 * 4] = b;
  }
  __syncthreads();

  unsigned int hh[16][2];

  // noise L1: 128 -> 128, all 8 waves (one col-tile each), output -> cols 128..255
  layer_run<128, 128, 1, 0, 8>(sH, wpk + O_NW0, fpk + F_NB0, nullptr, nullptr, hh, wave, lane);
  __syncthreads();
  writeback<1, 8>(sH + 128, hh, wave, lane);
  __syncthreads();

  // noise L2 (-> softplus head partials into accSt); then global L1 on all waves
  layer_run<128, 128, 1, 1, 8>(sH + 128, wpk + O_NW1, fpk + F_NB1, fpk + F_AW, accSt, hh, wave, lane);
  layer_run<128, 512, 4, 0, 8>(sH, wpk + O_GW0, fpk + F_GB0, nullptr, nullptr, hh, wave, lane);
  __syncthreads();
  writeback<4, 8>(sH, hh, wave, lane);   // h1 overwrites X + noise h (both dead)
  __syncthreads();

  // global L2: 512 -> 512
  layer_run<512, 512, 4, 0, 8>(sH, wpk + O_GW1, fpk + F_GB1, nullptr, nullptr, hh, wave, lane);
  __syncthreads();
  writeback<4, 8>(sH, hh, wave, lane);
  __syncthreads();

  // global L3: 512 -> 512, relu-dot with w_e -> mu partials
  layer_run<512, 512, 4, 1, 8>(sH, wpk + O_GW2, fpk + F_GB2, fpk + F_WE, accMu, hh, wave, lane);
  __syncthreads();

  if (tid < 64) {
    float mu = accMu[tid] + fpk[F_BE];
    float st = accSt[tid] + fpk[F_AB];
    out[blkTok + tid] = mu;
    out[NTOK + blkTok + tid] = log1pf(__expf(st)) + 1e-6f;
  }
}

// ---------------- launch ----------------
extern "C" void kernel_launch(void* const* d_in, const int* in_sizes, int n_in,
                              void* d_out, int out_size, void* d_ws, size_t ws_size,
                              hipStream_t stream) {
  const float* X     = (const float*)d_in[0];
  const float* gW0   = (const float*)d_in[1];
  const float* gbi0  = (const float*)d_in[2];
  const float* gbh0  = (const float*)d_in[3];
  const float* gW    = (const float*)d_in[4];
  const float* gbi   = (const float*)d_in[5];
  const float* gbh   = (const float*)d_in[6];
  const float* eW    = (const float*)d_in[7];
  const float* eb    = (const float*)d_in[8];
  const float* nW0   = (const float*)d_in[9];
  const float* nbi0  = (const float*)d_in[10];
  const float* nbh0  = (const float*)d_in[11];
  const float* nW    = (const float*)d_in[12];
  const float* nbi   = (const float*)d_in[13];
  const float* nbh   = (const float*)d_in[14];
  const float* aW    = (const float*)d_in[15];
  const float* ab    = (const float*)d_in[16];

  unsigned short* wpk = (unsigned short*)d_ws;
  float* fpk = (float*)((char*)d_ws + NWS * 2);

  long prepTotal = NWS + 1536 * 3 + 384 * 2 + 512 + 128 + 2;
  int prepBlocks = (int)((prepTotal + 255) / 256);
  prep_kernel<<<prepBlocks, 256, 0, stream>>>(gW0, gbi0, gbh0, gW, gbi, gbh, eW, eb,
                                              nW0, nbi0, nbh0, nW, nbi, nbh, aW, ab,
                                              wpk, fpk);
  dfrnn_main<<<3072, 512, 0, stream>>>(X, wpk, fpk, (float*)d_out);
}

// Round 3
// 1007.553 us; speedup vs baseline: 1.6685x; 1.6685x over previous
//
#include <hip/hip_runtime.h>

// ---------------- problem dims ----------------
#define IN_F  128
#define GHID  512
#define NHID  128
#define NTOK  196608L   // 1024 * 192
#define LDSP  520       // LDS row pitch in bf16 elems (512 + 8 pad)

typedef __attribute__((ext_vector_type(8))) short short8;
typedef __attribute__((ext_vector_type(4))) float floatx4;

// ---------------- ws layout ----------------
// bf16 packed weights (ushort elems), fragment order:
//   frag index = ((gate*(H/16) + tn) * (K/32) + tk), 512 elems per frag,
//   elem (lane,j): row n = tn*16 + (lane&15), col k = tk*32 + (lane>>4)*8 + j
#define O_GW0 0L
#define O_GW1 196608L
#define O_GW2 983040L
#define O_NW0 1769472L
#define O_NW1 1818624L
#define NWS   1867776L
// fp32 region (float elems), base byte = NWS*2
#define F_GB0 0
#define F_GB1 1536
#define F_GB2 3072
#define F_NB0 4608
#define F_NB1 4992
#define F_WE  5376
#define F_AW  5888
#define F_BE  6016
#define F_AB  6017

__device__ __forceinline__ unsigned short f2bf(float f) {
  unsigned int u = __float_as_uint(f);
  u += 0x7fffu + ((u >> 16) & 1u);      // RNE
  return (unsigned short)(u >> 16);
}
__device__ __forceinline__ float fsigm(float x) {
  return __builtin_amdgcn_rcpf(1.f + __expf(-x));
}
__device__ __forceinline__ float ftanh(float x) {
  return 1.f - 2.f * __builtin_amdgcn_rcpf(1.f + __expf(2.f * x));
}

// ---------------- prep kernel: repack weights ----------------
__device__ __forceinline__ long srcoff(long pp, int H, int K) {
  long f = pp >> 9;
  int r = (int)(pp & 511);
  int ln = r >> 3, j = r & 7;
  int nKT = K >> 5, nCT = H >> 4;
  int tk = (int)(f % nKT);
  long t2 = f / nKT;
  int tn = (int)(t2 % nCT);
  int gate = (int)(t2 / nCT);
  int n = tn * 16 + (ln & 15);
  int k = tk * 32 + ((ln >> 4) << 3) + j;
  int go = (gate == 0) ? 0 : ((gate == 1) ? 2 * H : 3 * H);  // i, c, o rows
  return (long)(go + n) * K + k;
}

__global__ void prep_kernel(
    const float* __restrict__ gW0, const float* __restrict__ gbi0, const float* __restrict__ gbh0,
    const float* __restrict__ gW,  const float* __restrict__ gbi,  const float* __restrict__ gbh,
    const float* __restrict__ eW,  const float* __restrict__ eb,
    const float* __restrict__ nW0, const float* __restrict__ nbi0, const float* __restrict__ nbh0,
    const float* __restrict__ nW,  const float* __restrict__ nbi,  const float* __restrict__ nbh,
    const float* __restrict__ aW,  const float* __restrict__ ab,
    unsigned short* __restrict__ wpk, float* __restrict__ fpk)
{
  long idx = (long)blockIdx.x * blockDim.x + threadIdx.x;
  if (idx < NWS) {
    const float* src;
    long off;
    if (idx < O_GW1)      { off = srcoff(idx - O_GW0, 512, 128); src = gW0; }
    else if (idx < O_GW2) { off = srcoff(idx - O_GW1, 512, 512); src = gW; }
    else if (idx < O_NW0) { off = srcoff(idx - O_GW2, 512, 512); src = gW + 1048576; }
    else if (idx < O_NW1) { off = srcoff(idx - O_NW0, 128, 128); src = nW0; }
    else                  { off = srcoff(idx - O_NW1, 128, 128); src = nW; }
    wpk[idx] = f2bf(src[off]);
    return;
  }
  long p = idx - NWS;
  if (p < 1536) { int g = (int)(p >> 9), n = (int)(p & 511);
    int o = (g == 0 ? 0 : (g == 1 ? 1024 : 1536)) + n;
    fpk[F_GB0 + p] = gbi0[o] + gbh0[o]; return; }
  p -= 1536;
  if (p < 1536) { int g = (int)(p >> 9), n = (int)(p & 511);
    int o = (g == 0 ? 0 : (g == 1 ? 1024 : 1536)) + n;
    fpk[F_GB1 + p] = gbi[o] + gbh[o]; return; }
  p -= 1536;
  if (p < 1536) { int g = (int)(p >> 9), n = (int)(p & 511);
    int o = (g == 0 ? 0 : (g == 1 ? 1024 : 1536)) + n;
    fpk[F_GB2 + p] = gbi[2048 + o] + gbh[2048 + o]; return; }
  p -= 1536;
  if (p < 384) { int g = (int)(p / 128), n = (int)(p % 128);
    int o = (g == 0 ? 0 : (g == 1 ? 256 : 384)) + n;
    fpk[F_NB0 + p] = nbi0[o] + nbh0[o]; return; }
  p -= 384;
  if (p < 384) { int g = (int)(p / 128), n = (int)(p % 128);
    int o = (g == 0 ? 0 : (g == 1 ? 256 : 384)) + n;
    fpk[F_NB1 + p] = nbi[o] + nbh[o]; return; }
  p -= 384;
  if (p < 512) { float s = 0.f;
    for (int f = 0; f < 10; ++f) s += eW[f * 512 + p];
    fpk[F_WE + p] = s; return; }
  p -= 512;
  if (p < 128) { fpk[F_AW + p] = aW[p]; return; }
  p -= 128;
  if (p == 0) { float s = 0.f; for (int f = 0; f < 10; ++f) s += eb[f]; fpk[F_BE] = s; return; }
  if (p == 1) { fpk[F_AB] = ab[0]; return; }
}

// ---------------- fused main kernel ----------------
// Layer engine, NO register bridge: ping-pong LDS buffers, epilogue writes h
// straight to sOut (disjoint from sIn). MODE 0: write bf16 h. MODE 1: relu-dot
// with dotw -> LDS atomics into accVec (no sOut).
// TT = token tiles per wave, CPW = col-tile passes, NW = col-tile stride.
template <int K, int H, int TT, int CPW, int NW, int MODE>
__device__ __forceinline__ void layer_run(
    const unsigned short* __restrict__ sIn,
    unsigned short* __restrict__ sOut,
    const unsigned short* __restrict__ wp,
    const float* __restrict__ bias,
    const float* __restrict__ dotw,
    float* accVec,
    int colTile0, int tokBase, int lane)
{
  constexpr int nKT = K / 32;
  constexpr int nCT = H / 16;
  float vv[TT][4];
  if constexpr (MODE == 1) {
#pragma unroll
    for (int tt = 0; tt < TT; ++tt)
#pragma unroll
      for (int r = 0; r < 4; ++r) vv[tt][r] = 0.f;
  }
#pragma unroll
  for (int cp = 0; cp < CPW; ++cp) {
    int tn = colTile0 + cp * NW;
    floatx4 acc[3][TT] = {};
    const unsigned short* wbase = wp + (size_t)tn * nKT * 512 + lane * 8;
    const unsigned short* aRow = sIn + (size_t)(tokBase + (lane & 15)) * LDSP + ((lane >> 4) << 3);
#pragma unroll 2
    for (int ks = 0; ks < nKT; ++ks) {
      short8 b0 = *(const short8*)(wbase + (size_t)ks * 512);
      short8 b1 = *(const short8*)(wbase + (size_t)(nCT * nKT + ks) * 512);
      short8 b2 = *(const short8*)(wbase + (size_t)(2 * nCT * nKT + ks) * 512);
#pragma unroll
      for (int tt = 0; tt < TT; ++tt) {
        short8 a = *(const short8*)(aRow + (size_t)tt * 16 * LDSP + ks * 32);
        acc[0][tt] = __builtin_amdgcn_mfma_f32_16x16x32_bf16(a, b0, acc[0][tt], 0, 0, 0);
        acc[1][tt] = __builtin_amdgcn_mfma_f32_16x16x32_bf16(a, b1, acc[1][tt], 0, 0, 0);
        acc[2][tt] = __builtin_amdgcn_mfma_f32_16x16x32_bf16(a, b2, acc[2][tt], 0, 0, 0);
      }
    }
    int colg = tn * 16 + (lane & 15);
    float bi = bias[colg], bc = bias[H + colg], bo = bias[2 * H + colg];
    float dw = 0.f;
    if constexpr (MODE == 1) dw = dotw[colg];
    int rbase = tokBase + ((lane >> 4) << 2);
#pragma unroll
    for (int tt = 0; tt < TT; ++tt) {
#pragma unroll
      for (int r = 0; r < 4; ++r) {
        float gi = acc[0][tt][r] + bi;
        float gc = acc[1][tt][r] + bc;
        float go = acc[2][tt][r] + bo;
        float h = fsigm(go) * ftanh(fsigm(gi) * ftanh(gc));
        if constexpr (MODE == 0) {
          sOut[(size_t)(rbase + tt * 16 + r) * LDSP + colg] = f2bf(h);
        } else {
          vv[tt][r] += fmaxf(h, 0.f) * dw;
        }
      }
    }
  }
  if constexpr (MODE == 1) {
#pragma unroll
    for (int tt = 0; tt < TT; ++tt)
#pragma unroll
      for (int r = 0; r < 4; ++r) {
        float v = vv[tt][r];
        v += __shfl_xor(v, 1, 16);
        v += __shfl_xor(v, 2, 16);
        v += __shfl_xor(v, 4, 16);
        v += __shfl_xor(v, 8, 16);
        if ((lane & 15) == 0)
          atomicAdd(&accVec[tokBase + tt * 16 + ((lane >> 4) << 2) + r], v);
      }
  }
}

// 1024 threads = 16 waves = 1 block/CU (LDS 133.6 KB). waves_per_eu(4,4) pins
// the allocator at exactly 4 waves/SIMD -> full 128-reg budget, no spills
// (R2 lesson: min-only bound let the heuristic pick 64 regs + spill).
__attribute__((amdgpu_waves_per_eu(4, 4)))
__global__ __launch_bounds__(1024) void dfrnn_main(
    const float* __restrict__ X,
    const unsigned short* __restrict__ wpk,
    const float* __restrict__ fpk,
    float* __restrict__ out)
{
  __shared__ __align__(16) unsigned short bufA[64 * LDSP];
  __shared__ __align__(16) unsigned short bufB[64 * LDSP];
  __shared__ float accMu[64];
  __shared__ float accSt[64];
  int tid = threadIdx.x;
  int wave = tid >> 6, lane = tid & 63;
  size_t blkTok = (size_t)blockIdx.x * 64;

  if (tid < 64) { accMu[tid] = 0.f; accSt[tid] = 0.f; }
  // load X tile [64 x 128] fp32 -> bf16 into bufA cols 0..127
  for (int i = tid; i < 64 * 32; i += 1024) {
    int row = i >> 5, c4 = i & 31;
    float4 v = *(const float4*)(X + (blkTok + row) * 128 + c4 * 4);
    ushort4 b;
    b.x = f2bf(v.x); b.y = f2bf(v.y); b.z = f2bf(v.z); b.w = f2bf(v.w);
    *(ushort4*)&bufA[(size_t)row * LDSP + c4 * 4] = b;
  }
  __syncthreads();

  // noise L1: A[0..128) -> A[128..256)  (disjoint cols, safe in-flight)
  // 16 waves: col tile = wave&7, token half = (wave>>3)*32, TT=2
  layer_run<128, 128, 2, 1, 8, 0>(bufA, bufA + 128, wpk + O_NW0, fpk + F_NB0,
                                  nullptr, nullptr, wave & 7, (wave >> 3) * 32, lane);
  __syncthreads();

  // noise L2: A[128..256) -> accSt (MODE 1); then global L1: A[0..128) -> B
  layer_run<128, 128, 2, 1, 8, 1>(bufA + 128, nullptr, wpk + O_NW1, fpk + F_NB1,
                                  fpk + F_AW, accSt, wave & 7, (wave >> 3) * 32, lane);
  layer_run<128, 512, 4, 2, 16, 0>(bufA, bufB, wpk + O_GW0, fpk + F_GB0,
                                   nullptr, nullptr, wave, 0, lane);
  __syncthreads();

  // global L2: B -> A (overwrites X + noise h, both dead; barrier above covers nL2 reads)
  layer_run<512, 512, 4, 2, 16, 0>(bufB, bufA, wpk + O_GW1, fpk + F_GB1,
                                   nullptr, nullptr, wave, 0, lane);
  __syncthreads();

  // global L3: A -> accMu (relu-dot with w_e)
  layer_run<512, 512, 4, 2, 16, 1>(bufA, nullptr, wpk + O_GW2, fpk + F_GB2,
                                   fpk + F_WE, accMu, wave, 0, lane);
  __syncthreads();

  if (tid < 64) {
    float mu = accMu[tid] + fpk[F_BE];
    float st = accSt[tid] + fpk[F_AB];
    out[blkTok + tid] = mu;
    out[NTOK + blkTok + tid] = log1pf(__expf(st)) + 1e-6f;
  }
}

// ---------------- launch ----------------
extern "C" void kernel_launch(void* const* d_in, const int* in_sizes, int n_in,
                              void* d_out, int out_size, void* d_ws, size_t ws_size,
                              hipStream_t stream) {
  const float* X     = (const float*)d_in[0];
  const float* gW0   = (const float*)d_in[1];
  const float* gbi0  = (const float*)d_in[2];
  const float* gbh0  = (const float*)d_in[3];
  const float* gW    = (const float*)d_in[4];
  const float* gbi   = (const float*)d_in[5];
  const float* gbh   = (const float*)d_in[6];
  const float* eW    = (const float*)d_in[7];
  const float* eb    = (const float*)d_in[8];
  const float* nW0   = (const float*)d_in[9];
  const float* nbi0  = (const float*)d_in[10];
  const float* nbh0  = (const float*)d_in[11];
  const float* nW    = (const float*)d_in[12];
  const float* nbi   = (const float*)d_in[13];
  const float* nbh   = (const float*)d_in[14];
  const float* aW    = (const float*)d_in[15];
  const float* ab    = (const float*)d_in[16];

  unsigned short* wpk = (unsigned short*)d_ws;
  float* fpk = (float*)((char*)d_ws + NWS * 2);

  long prepTotal = NWS + 1536 * 3 + 384 * 2 + 512 + 128 + 2;
  int prepBlocks = (int)((prepTotal + 255) / 256);
  prep_kernel<<<prepBlocks, 256, 0, stream>>>(gW0, gbi0, gbh0, gW, gbi, gbh, eW, eb,
                                              nW0, nbi0, nbh0, nW, nbi, nbh, aW, ab,
                                              wpk, fpk);
  dfrnn_main<<<3072, 1024, 0, stream>>>(X, wpk, fpk, (float*)d_out);
}